// Round 2
// baseline (716.854 us; speedup 1.0000x reference)
//
#include <hip/hip_runtime.h>
#include <hip/hip_bf16.h>
#include <math.h>

typedef __bf16 bf16;
typedef __attribute__((ext_vector_type(8))) __bf16 bf16x8;
typedef __attribute__((ext_vector_type(4))) __bf16 bf16x4;
typedef __attribute__((ext_vector_type(4))) float f32x4;

#define B_  4
#define L_  2048
#define D_  2048
#define R_  2048
#define DH_ 512
#define M_  (B_ * L_)   // 8192

// ---- async global->LDS, 16B per lane; LDS dest must be wave-uniform ----
__device__ __forceinline__ void gload16(const void* g, void* l) {
    __builtin_amdgcn_global_load_lds(
        (__attribute__((address_space(1))) void*)(uintptr_t)g,
        (__attribute__((address_space(3))) void*)l,
        16, 0, 0);
}

// ---------------- f32 -> bf16 convert (vectorized 4x) ----------------
__global__ void k_cvt(const float* __restrict__ in, bf16* __restrict__ out, int n4) {
    int i = blockIdx.x * blockDim.x + threadIdx.x;
    if (i >= n4) return;
    float4 v = reinterpret_cast<const float4*>(in)[i];
    bf16x4 o = { (bf16)v.x, (bf16)v.y, (bf16)v.z, (bf16)v.w };
    reinterpret_cast<bf16x4*>(out)[i] = o;
}

// ---------------- depthwise conv (k=3, pad 1) over L; writes t_out to d_out ----------------
__global__ void k_conv(const float* __restrict__ x, const float* __restrict__ w,
                       const float* __restrict__ cb, float* __restrict__ out) {
    int idx = blockIdx.x * blockDim.x + threadIdx.x;   // (b*L+l)*512 + dq
    int dq = idx & (D_/4 - 1);
    int bl = idx >> 9;                                 // b*L + l
    int l  = bl & (L_ - 1);
    int d0 = dq * 4;
    const float4* xp = reinterpret_cast<const float4*>(x);
    float4 xc = xp[idx];
    float4 xm = (l > 0)      ? xp[idx - D_/4] : make_float4(0.f,0.f,0.f,0.f);
    float4 xq = (l < L_ - 1) ? xp[idx + D_/4] : make_float4(0.f,0.f,0.f,0.f);
    const float* pm = (const float*)&xm;
    const float* pc = (const float*)&xc;
    const float* pq = (const float*)&xq;
    float4 r;
    float* pr = (float*)&r;
    #pragma unroll
    for (int j = 0; j < 4; ++j) {
        int d = d0 + j;
        pr[j] = pm[j]*w[d*3+0] + pc[j]*w[d*3+1] + pq[j]*w[d*3+2] + cb[d];
    }
    reinterpret_cast<float4*>(out)[idx] = r;
}

// ---------------- bf16 MFMA GEMM: out[m,n] = sum_k A[m,k]*W[n,k] (+bias[n]) ----------------
// EPI: 0 = bias, store bf16 | 1 = relu+bias, bf16 | 2 = sigmoid+bias, bf16 | 3 = add into f32 out
template<int EPI>
__global__ __launch_bounds__(256)
void k_gemm(const bf16* __restrict__ A, const bf16* __restrict__ W,
            const float* __restrict__ bias, bf16* __restrict__ ob,
            float* __restrict__ of, int N, int K)
{
    __shared__ __align__(16) bf16 As[128 * 32];
    __shared__ __align__(16) bf16 Bs[128 * 32];
    const int t    = threadIdx.x;
    const int lane = t & 63;
    const int wv   = t >> 6;
    const int wr   = wv >> 1, wc = wv & 1;
    const int bm   = blockIdx.y, bn = blockIdx.x;
    const bf16* Ab = A + (size_t)bm * 128 * K;
    const bf16* Wb = W + (size_t)bn * 128 * K;
    const int r0 = t >> 2;             // staged row (first 64)
    const int kq = (t & 3) * 8;        // staged k offset (elems)
    char* ldsA = (char*)As + wv * 1024;
    char* ldsB = (char*)Bs + wv * 1024;

    f32x4 acc[4][4] = {};

    const int fr = lane & 15;          // fragment row/col within 16
    const int fk = (lane >> 4) * 8;    // fragment k offset

    for (int kt = 0; kt < K; kt += 32) {
        const bf16* ak = Ab + (size_t)r0 * K + kt + kq;
        const bf16* wk = Wb + (size_t)r0 * K + kt + kq;
        gload16(ak,                 ldsA);
        gload16(ak + (size_t)64*K,  ldsA + 4096);
        gload16(wk,                 ldsB);
        gload16(wk + (size_t)64*K,  ldsB + 4096);
        __syncthreads();   // drains vmcnt -> tile ready
        bf16x8 af[4], bw[4];
        #pragma unroll
        for (int i = 0; i < 4; ++i) {
            af[i] = *(const bf16x8*)&As[(wr*64 + i*16 + fr) * 32 + fk];
            bw[i] = *(const bf16x8*)&Bs[(wc*64 + i*16 + fr) * 32 + fk];
        }
        #pragma unroll
        for (int mi = 0; mi < 4; ++mi)
            #pragma unroll
            for (int ni = 0; ni < 4; ++ni)
                acc[mi][ni] = __builtin_amdgcn_mfma_f32_16x16x32_bf16(
                    af[mi], bw[ni], acc[mi][ni], 0, 0, 0);
        __syncthreads();   // all reads done before next stage overwrites
    }

    const int fq = lane >> 4;
    #pragma unroll
    for (int mi = 0; mi < 4; ++mi) {
        #pragma unroll
        for (int ni = 0; ni < 4; ++ni) {
            const int row0 = bm*128 + wr*64 + mi*16 + fq*4;
            const int col  = bn*128 + wc*64 + ni*16 + fr;
            float bb = (EPI == 3) ? 0.f : bias[col];
            #pragma unroll
            for (int j = 0; j < 4; ++j) {
                float v = acc[mi][ni][j] + bb;
                size_t o = (size_t)(row0 + j) * N + col;
                if      (EPI == 0) ob[o] = (bf16)v;
                else if (EPI == 1) ob[o] = (bf16)fmaxf(v, 0.f);
                else if (EPI == 2) ob[o] = (bf16)(1.f / (1.f + __expf(-v)));
                else               of[o] = of[o] + v;
            }
        }
    }
}

// ---------------- prefix scan over L, split into 16 chunks of 128 ----------------
// thread per (b, chunk, r): idx = ((b*16 + ch) << 11) | r
__global__ void k_scan_sum(const bf16* __restrict__ U, const bf16* __restrict__ G,
                           float* __restrict__ CS) {
    int idx = blockIdx.x * blockDim.x + threadIdx.x;   // B*16*R = 131072
    int r  = idx & (R_ - 1);
    int ch = (idx >> 11) & 15;
    int b  = idx >> 15;
    size_t base = ((size_t)(b * L_ + ch * 128)) * R_ + r;
    float s = 0.f;
    #pragma unroll 8
    for (int i = 0; i < 128; ++i) {
        float u = (float)U[base + (size_t)i * R_];
        float g = (float)G[base + (size_t)i * R_];
        s = fmaf(u, g, s);
    }
    CS[idx] = s;
}

__global__ void k_scan_apply(const bf16* __restrict__ U, const bf16* __restrict__ V,
                             const bf16* __restrict__ G, const float* __restrict__ CS,
                             bf16* __restrict__ GB) {
    int idx = blockIdx.x * blockDim.x + threadIdx.x;
    int r  = idx & (R_ - 1);
    int ch = (idx >> 11) & 15;
    int b  = idx >> 15;
    float run = 0.f;
    for (int c = 0; c < ch; ++c)
        run += CS[(((b << 4) + c) << 11) + r];
    size_t base = ((size_t)(b * L_ + ch * 128)) * R_ + r;
    #pragma unroll 4
    for (int i = 0; i < 128; ++i) {
        size_t o = base + (size_t)i * R_;
        float u = (float)U[o];
        float g = (float)G[o];
        float v = (float)V[o];
        run = fmaf(u, g, run);
        GB[o] = (bf16)(run * v * g);
    }
}

extern "C" void kernel_launch(void* const* d_in, const int* in_sizes, int n_in,
                              void* d_out, int out_size, void* d_ws, size_t ws_size,
                              hipStream_t stream)
{
    const float* x   = (const float*)d_in[0];
    const float* Wu  = (const float*)d_in[1];
    const float* bu  = (const float*)d_in[2];
    const float* Wv  = (const float*)d_in[3];
    const float* bv  = (const float*)d_in[4];
    const float* Wg1 = (const float*)d_in[5];
    const float* bg1 = (const float*)d_in[6];
    const float* Wg2 = (const float*)d_in[7];
    const float* bg2 = (const float*)d_in[8];
    const float* cw  = (const float*)d_in[9];
    const float* cb  = (const float*)d_in[10];
    float* out = (float*)d_out;

    char* w = (char*)d_ws;
    bf16* xb   = (bf16*)w;  w += (size_t)M_ * D_  * 2;
    bf16* Wub  = (bf16*)w;  w += (size_t)R_ * D_  * 2;
    bf16* Wvb  = (bf16*)w;  w += (size_t)R_ * D_  * 2;
    bf16* Wg1b = (bf16*)w;  w += (size_t)DH_* D_  * 2;
    bf16* Wg2b = (bf16*)w;  w += (size_t)R_ * DH_ * 2;
    bf16* U    = (bf16*)w;  w += (size_t)M_ * R_  * 2;
    bf16* V    = (bf16*)w;  w += (size_t)M_ * R_  * 2;
    bf16* H    = (bf16*)w;  w += (size_t)M_ * DH_ * 2;
    bf16* GT   = (bf16*)w;  w += (size_t)M_ * R_  * 2;
    bf16* GB   = (bf16*)w;  w += (size_t)M_ * R_  * 2;
    float* CS  = (float*)w; w += (size_t)B_ * 16 * R_ * 4;

    // converts
    k_cvt<<<M_*D_/4/256,  256, 0, stream>>>(x,   xb,   M_*D_/4);
    k_cvt<<<R_*D_/4/256,  256, 0, stream>>>(Wu,  Wub,  R_*D_/4);
    k_cvt<<<R_*D_/4/256,  256, 0, stream>>>(Wv,  Wvb,  R_*D_/4);
    k_cvt<<<DH_*D_/4/256, 256, 0, stream>>>(Wg1, Wg1b, DH_*D_/4);
    k_cvt<<<R_*DH_/4/256, 256, 0, stream>>>(Wg2, Wg2b, R_*DH_/4);

    // depthwise conv -> d_out (t_out term)
    k_conv<<<M_*D_/4/256, 256, 0, stream>>>(x, cw, cb, out);

    // projections
    k_gemm<0><<<dim3(R_/128,  M_/128), 256, 0, stream>>>(xb, Wub,  bu,  U,  nullptr, R_,  D_);
    k_gemm<0><<<dim3(R_/128,  M_/128), 256, 0, stream>>>(xb, Wvb,  bv,  V,  nullptr, R_,  D_);
    k_gemm<1><<<dim3(DH_/128, M_/128), 256, 0, stream>>>(xb, Wg1b, bg1, H,  nullptr, DH_, D_);
    k_gemm<2><<<dim3(R_/128,  M_/128), 256, 0, stream>>>(H,  Wg2b, bg2, GT, nullptr, R_,  DH_);

    // gated prefix scan -> GB = cumsum(u*g) * (v*g)
    k_scan_sum  <<<B_*16*R_/256, 256, 0, stream>>>(U, GT, CS);
    k_scan_apply<<<B_*16*R_/256, 256, 0, stream>>>(U, V, GT, CS, GB);

    // uv_term: d_out += GB @ Wu^T  (contract rank, same (N,K) buffer layout)
    k_gemm<3><<<dim3(D_/128, M_/128), 256, 0, stream>>>(GB, Wub, nullptr, nullptr, out, D_, R_);
}

// Round 5
// 567.297 us; speedup vs baseline: 1.2636x; 1.2636x over previous
//
#include <hip/hip_runtime.h>
#include <hip/hip_bf16.h>
#include <math.h>

typedef __bf16 bf16;
typedef __attribute__((ext_vector_type(8))) __bf16 bf16x8;
typedef __attribute__((ext_vector_type(4))) __bf16 bf16x4;
typedef __attribute__((ext_vector_type(4))) float f32x4;

#define B_  4
#define L_  2048
#define D_  2048
#define R_  2048
#define DH_ 512
#define M_  (B_ * L_)   // 8192

// ---- async global->LDS, 16B per lane; LDS dest is wave-uniform base + lane*16 ----
__device__ __forceinline__ void gload16(const void* g, void* l) {
    __builtin_amdgcn_global_load_lds(
        (__attribute__((address_space(1))) void*)(uintptr_t)g,
        (__attribute__((address_space(3))) void*)l,
        16, 0, 0);
}

// T2 swizzle: tile row r (0-255), k-unit cu (0-3, 8 bf16 each) -> byte offset in 16KB tile
__device__ __forceinline__ int swz(int r, int cu) {
    return r * 64 + (((cu ^ (r >> 1)) & 3) << 4);
}

// ---------------- f32 -> bf16 convert (vectorized 4x) ----------------
__global__ void k_cvt(const float* __restrict__ in, bf16* __restrict__ out, int n4) {
    int i = blockIdx.x * blockDim.x + threadIdx.x;
    if (i >= n4) return;
    float4 v = reinterpret_cast<const float4*>(in)[i];
    bf16x4 o = { (bf16)v.x, (bf16)v.y, (bf16)v.z, (bf16)v.w };
    reinterpret_cast<bf16x4*>(out)[i] = o;
}

// ---------------- depthwise conv (k=3, pad 1) over L; writes t_out to d_out ----------------
__global__ void k_conv(const float* __restrict__ x, const float* __restrict__ w,
                       const float* __restrict__ cb, float* __restrict__ out) {
    int idx = blockIdx.x * blockDim.x + threadIdx.x;   // (b*L+l)*512 + dq
    int dq = idx & (D_/4 - 1);
    int bl = idx >> 9;
    int l  = bl & (L_ - 1);
    int d0 = dq * 4;
    const float4* xp = reinterpret_cast<const float4*>(x);
    float4 xc = xp[idx];
    float4 xm = (l > 0)      ? xp[idx - D_/4] : make_float4(0.f,0.f,0.f,0.f);
    float4 xq = (l < L_ - 1) ? xp[idx + D_/4] : make_float4(0.f,0.f,0.f,0.f);
    const float* pm = (const float*)&xm;
    const float* pc = (const float*)&xc;
    const float* pq = (const float*)&xq;
    float4 r;
    float* pr = (float*)&r;
    #pragma unroll
    for (int j = 0; j < 4; ++j) {
        int d = d0 + j;
        pr[j] = pm[j]*w[d*3+0] + pc[j]*w[d*3+1] + pq[j]*w[d*3+2] + cb[d];
    }
    reinterpret_cast<float4*>(out)[idx] = r;
}

// ============ 256x256 8-phase-style GEMM: out[m,n] = sum_k A[m,k]*W[n,k] ============
// BK=32, 3 LDS buffers, prefetch 2 K-tiles ahead, counted vmcnt(4), T2 swizzle, T5 setprio.
// EPI: 0 = bias, bf16 | 2 = sigmoid+bias, bf16 | 3 = add into f32 out
template<int EPI>
__global__ __launch_bounds__(512, 2)
void k_gemm2(const bf16* __restrict__ A, const bf16* __restrict__ W,
             const float* __restrict__ bias, bf16* __restrict__ ob,
             float* __restrict__ of, int N, int K)
{
    __shared__ __align__(16) char lds[98304];   // 3 x (A 16KB + B 16KB)
    const int t    = threadIdx.x;
    const int lane = t & 63;
    const int w8   = t >> 6;        // wave 0-7
    const int wr   = w8 >> 2;       // row group (128 rows)
    const int wc   = w8 & 3;        // col group (64 cols)
    const int bm   = blockIdx.y, bn = blockIdx.x;
    const bf16* Ab = A + (size_t)bm * 256 * K;
    const bf16* Wb = W + (size_t)bn * 256 * K;
    const int NT = K >> 5;          // K-tiles of 32

    // staging map: thread t stages 16B unit t of each 8KB chunk
    const int sr0 = t >> 2;                    // row within 128-row half
    const int sc  = t & 3;                     // LDS col-unit (post-swizzle)
    const int scc = (sc ^ (sr0 >> 1)) & 3;     // global col-unit (pre-swizzled source)
    const int fr  = lane & 15;
    const int cu  = lane >> 4;
    const int wbase = w8 << 10;

    const bf16* gaB = Ab + (size_t)sr0 * K + scc * 8;   // + ts*32 per tile
    const bf16* gbB = Wb + (size_t)sr0 * K + scc * 8;

    f32x4 acc[8][4] = {};

    // ---- prologue: stage tiles 0 and 1 ----
    {
        char* A0 = lds;          char* B0 = lds + 16384;
        char* A1 = lds + 32768;  char* B1 = lds + 49152;
        const bf16* ga = gaB;  const bf16* gb = gbB;
        gload16(ga,                   A0 + wbase);
        gload16(ga + (size_t)128 * K, A0 + 8192 + wbase);
        gload16(gb,                   B0 + wbase);
        gload16(gb + (size_t)128 * K, B0 + 8192 + wbase);
        int t1 = (NT > 1) ? 1 : 0;
        ga = gaB + t1 * 32;  gb = gbB + t1 * 32;
        gload16(ga,                   A1 + wbase);
        gload16(ga + (size_t)128 * K, A1 + 8192 + wbase);
        gload16(gb,                   B1 + wbase);
        gload16(gb + (size_t)128 * K, B1 + 8192 + wbase);
    }
    asm volatile("s_waitcnt vmcnt(4)" ::: "memory");   // tile 0 landed; tile 1 in flight
    __builtin_amdgcn_s_barrier();

    int cur = 0;
    for (int tt = 0; tt < NT; ++tt) {
        const char* Al = lds + cur * 32768;
        const char* Bl = Al + 16384;
        int nb = cur + 2; if (nb >= 3) nb -= 3;
        int ts = tt + 2; if (ts >= NT) ts = NT - 1;    // clamped tail keeps counts uniform
        char* An = lds + nb * 32768;
        char* Bn = An + 16384;
        const bf16* ga = gaB + ts * 32;
        const bf16* gb = gbB + ts * 32;

        bf16x8 bfrag[4], afrag[4];

        // ---- phase 1: rows [0,64) of wave's 128, all 64 cols ----
        #pragma unroll
        for (int n = 0; n < 4; ++n)
            bfrag[n] = *(const bf16x8*)(Bl + swz(wc*64 + n*16 + fr, cu));
        #pragma unroll
        for (int g = 0; g < 4; ++g)
            afrag[g] = *(const bf16x8*)(Al + swz(wr*128 + g*16 + fr, cu));
        gload16(ga,                   An + wbase);           // stage A of tile tt+2
        gload16(ga + (size_t)128 * K, An + 8192 + wbase);
        __builtin_amdgcn_s_barrier();
        __builtin_amdgcn_s_setprio(1);
        #pragma unroll
        for (int g = 0; g < 4; ++g)
            #pragma unroll
            for (int n = 0; n < 4; ++n)
                acc[g][n] = __builtin_amdgcn_mfma_f32_16x16x32_bf16(
                    afrag[g], bfrag[n], acc[g][n], 0, 0, 0);
        __builtin_amdgcn_s_setprio(0);
        __builtin_amdgcn_s_barrier();

        // ---- phase 2: rows [64,128); B-frags reused ----
        #pragma unroll
        for (int g = 0; g < 4; ++g)
            afrag[g] = *(const bf16x8*)(Al + swz(wr*128 + 64 + g*16 + fr, cu));
        gload16(gb,                   Bn + wbase);           // stage B of tile tt+2
        gload16(gb + (size_t)128 * K, Bn + 8192 + wbase);
        __builtin_amdgcn_s_barrier();
        __builtin_amdgcn_s_setprio(1);
        #pragma unroll
        for (int g = 0; g < 4; ++g)
            #pragma unroll
            for (int n = 0; n < 4; ++n)
                acc[4+g][n] = __builtin_amdgcn_mfma_f32_16x16x32_bf16(
                    afrag[g], bfrag[n], acc[4+g][n], 0, 0, 0);
        __builtin_amdgcn_s_setprio(0);
        // counted wait: allow tile tt+2's 4 loads in flight; tile tt+1 fully landed
        asm volatile("s_waitcnt vmcnt(4)" ::: "memory");
        __builtin_amdgcn_s_barrier();

        cur = cur + 1; if (cur >= 3) cur -= 3;
    }

    // ---- epilogue ----
    const int fq = lane >> 4;
    #pragma unroll
    for (int g = 0; g < 8; ++g) {
        #pragma unroll
        for (int n = 0; n < 4; ++n) {
            const int row0 = bm*256 + wr*128 + g*16 + fq*4;
            const int col  = bn*256 + wc*64 + n*16 + fr;
            float bb = (EPI == 3) ? 0.f : bias[col];
            #pragma unroll
            for (int j = 0; j < 4; ++j) {
                float v = acc[g][n][j] + bb;
                size_t o = (size_t)(row0 + j) * N + col;
                if      (EPI == 0) ob[o] = (bf16)v;
                else if (EPI == 2) ob[o] = (bf16)(1.f / (1.f + __expf(-v)));
                else               of[o] = of[o] + v;
            }
        }
    }
}

// ---------------- 128x128 2-phase GEMM (kept for N=512 gate GEMM) ----------------
// EPI: 1 = relu+bias, bf16
template<int EPI>
__global__ __launch_bounds__(256)
void k_gemm(const bf16* __restrict__ A, const bf16* __restrict__ W,
            const float* __restrict__ bias, bf16* __restrict__ ob,
            float* __restrict__ of, int N, int K)
{
    __shared__ __align__(16) bf16 As[128 * 32];
    __shared__ __align__(16) bf16 Bs[128 * 32];
    const int t    = threadIdx.x;
    const int lane = t & 63;
    const int wv   = t >> 6;
    const int wr   = wv >> 1, wc = wv & 1;
    const int bm   = blockIdx.y, bn = blockIdx.x;
    const bf16* Ab = A + (size_t)bm * 128 * K;
    const bf16* Wb = W + (size_t)bn * 128 * K;
    const int r0 = t >> 2;
    const int kq = (t & 3) * 8;
    char* ldsA = (char*)As + wv * 1024;
    char* ldsB = (char*)Bs + wv * 1024;

    f32x4 acc[4][4] = {};
    const int fr = lane & 15;
    const int fk = (lane >> 4) * 8;

    for (int kt = 0; kt < K; kt += 32) {
        const bf16* ak = Ab + (size_t)r0 * K + kt + kq;
        const bf16* wk = Wb + (size_t)r0 * K + kt + kq;
        gload16(ak,                 ldsA);
        gload16(ak + (size_t)64*K,  ldsA + 4096);
        gload16(wk,                 ldsB);
        gload16(wk + (size_t)64*K,  ldsB + 4096);
        __syncthreads();
        bf16x8 af[4], bw[4];
        #pragma unroll
        for (int i = 0; i < 4; ++i) {
            af[i] = *(const bf16x8*)&As[(wr*64 + i*16 + fr) * 32 + fk];
            bw[i] = *(const bf16x8*)&Bs[(wc*64 + i*16 + fr) * 32 + fk];
        }
        #pragma unroll
        for (int mi = 0; mi < 4; ++mi)
            #pragma unroll
            for (int ni = 0; ni < 4; ++ni)
                acc[mi][ni] = __builtin_amdgcn_mfma_f32_16x16x32_bf16(
                    af[mi], bw[ni], acc[mi][ni], 0, 0, 0);
        __syncthreads();
    }

    const int fq = lane >> 4;
    #pragma unroll
    for (int mi = 0; mi < 4; ++mi) {
        #pragma unroll
        for (int ni = 0; ni < 4; ++ni) {
            const int row0 = bm*128 + wr*64 + mi*16 + fq*4;
            const int col  = bn*128 + wc*64 + ni*16 + fr;
            float bb = bias[col];
            #pragma unroll
            for (int j = 0; j < 4; ++j) {
                float v = acc[mi][ni][j] + bb;
                size_t o = (size_t)(row0 + j) * N + col;
                ob[o] = (bf16)fmaxf(v, 0.f);
            }
        }
    }
}

// ---------------- prefix scan over L, split into 16 chunks of 128 ----------------
__global__ void k_scan_sum(const bf16* __restrict__ U, const bf16* __restrict__ G,
                           float* __restrict__ CS) {
    int idx = blockIdx.x * blockDim.x + threadIdx.x;   // B*16*R = 131072
    int r  = idx & (R_ - 1);
    int ch = (idx >> 11) & 15;
    int b  = idx >> 15;
    size_t base = ((size_t)(b * L_ + ch * 128)) * R_ + r;
    float s = 0.f;
    #pragma unroll 8
    for (int i = 0; i < 128; ++i) {
        float u = (float)U[base + (size_t)i * R_];
        float g = (float)G[base + (size_t)i * R_];
        s = fmaf(u, g, s);
    }
    CS[idx] = s;
}

__global__ void k_scan_apply(const bf16* __restrict__ U, const bf16* __restrict__ V,
                             const bf16* __restrict__ G, const float* __restrict__ CS,
                             bf16* __restrict__ GB) {
    int idx = blockIdx.x * blockDim.x + threadIdx.x;
    int r  = idx & (R_ - 1);
    int ch = (idx >> 11) & 15;
    int b  = idx >> 15;
    float run = 0.f;
    for (int c = 0; c < ch; ++c)
        run += CS[(((b << 4) + c) << 11) + r];
    size_t base = ((size_t)(b * L_ + ch * 128)) * R_ + r;
    #pragma unroll 4
    for (int i = 0; i < 128; ++i) {
        size_t o = base + (size_t)i * R_;
        float u = (float)U[o];
        float g = (float)G[o];
        float v = (float)V[o];
        run = fmaf(u, g, run);
        GB[o] = (bf16)(run * v * g);
    }
}

extern "C" void kernel_launch(void* const* d_in, const int* in_sizes, int n_in,
                              void* d_out, int out_size, void* d_ws, size_t ws_size,
                              hipStream_t stream)
{
    const float* x   = (const float*)d_in[0];
    const float* Wu  = (const float*)d_in[1];
    const float* bu  = (const float*)d_in[2];
    const float* Wv  = (const float*)d_in[3];
    const float* bv  = (const float*)d_in[4];
    const float* Wg1 = (const float*)d_in[5];
    const float* bg1 = (const float*)d_in[6];
    const float* Wg2 = (const float*)d_in[7];
    const float* bg2 = (const float*)d_in[8];
    const float* cw  = (const float*)d_in[9];
    const float* cb  = (const float*)d_in[10];
    float* out = (float*)d_out;

    char* w = (char*)d_ws;
    bf16* xb   = (bf16*)w;  w += (size_t)M_ * D_  * 2;
    bf16* Wub  = (bf16*)w;  w += (size_t)R_ * D_  * 2;
    bf16* Wvb  = (bf16*)w;  w += (size_t)R_ * D_  * 2;
    bf16* Wg1b = (bf16*)w;  w += (size_t)DH_* D_  * 2;
    bf16* Wg2b = (bf16*)w;  w += (size_t)R_ * DH_ * 2;
    bf16* U    = (bf16*)w;  w += (size_t)M_ * R_  * 2;
    bf16* V    = (bf16*)w;  w += (size_t)M_ * R_  * 2;
    bf16* H    = (bf16*)w;  w += (size_t)M_ * DH_ * 2;
    bf16* GT   = (bf16*)w;  w += (size_t)M_ * R_  * 2;
    bf16* GB   = (bf16*)w;  w += (size_t)M_ * R_  * 2;
    float* CS  = (float*)w; w += (size_t)B_ * 16 * R_ * 4;

    // converts
    k_cvt<<<M_*D_/4/256,  256, 0, stream>>>(x,   xb,   M_*D_/4);
    k_cvt<<<R_*D_/4/256,  256, 0, stream>>>(Wu,  Wub,  R_*D_/4);
    k_cvt<<<R_*D_/4/256,  256, 0, stream>>>(Wv,  Wvb,  R_*D_/4);
    k_cvt<<<DH_*D_/4/256, 256, 0, stream>>>(Wg1, Wg1b, DH_*D_/4);
    k_cvt<<<R_*DH_/4/256, 256, 0, stream>>>(Wg2, Wg2b, R_*DH_/4);

    // depthwise conv -> d_out (t_out term)
    k_conv<<<M_*D_/4/256, 256, 0, stream>>>(x, cw, cb, out);

    // projections (256^2 pipelined kernel for the N=2048 GEMMs)
    k_gemm2<0><<<dim3(R_/256,  M_/256), 512, 0, stream>>>(xb, Wub,  bu,  U,  nullptr, R_,  D_);
    k_gemm2<0><<<dim3(R_/256,  M_/256), 512, 0, stream>>>(xb, Wvb,  bv,  V,  nullptr, R_,  D_);
    k_gemm<1> <<<dim3(DH_/128, M_/128), 256, 0, stream>>>(xb, Wg1b, bg1, H,  nullptr, DH_, D_);
    k_gemm2<2><<<dim3(R_/256,  M_/256), 512, 0, stream>>>(H,  Wg2b, bg2, GT, nullptr, R_,  DH_);

    // gated prefix scan -> GB = cumsum(u*g) * (v*g)
    k_scan_sum  <<<B_*16*R_/256, 256, 0, stream>>>(U, GT, CS);
    k_scan_apply<<<B_*16*R_/256, 256, 0, stream>>>(U, V, GT, CS, GB);

    // uv_term: d_out += GB @ Wu^T
    k_gemm2<3><<<dim3(D_/256, M_/256), 512, 0, stream>>>(GB, Wub, nullptr, nullptr, out, D_, R_);
}

// Round 10
// 556.134 us; speedup vs baseline: 1.2890x; 1.0201x over previous
//
#include <hip/hip_runtime.h>
#include <hip/hip_bf16.h>
#include <math.h>

typedef __bf16 bf16;
typedef __attribute__((ext_vector_type(8))) __bf16 bf16x8;
typedef __attribute__((ext_vector_type(4))) __bf16 bf16x4;
typedef __attribute__((ext_vector_type(4))) float f32x4;

#define B_  4
#define L_  2048
#define D_  2048
#define R_  2048
#define DH_ 512
#define M_  (B_ * L_)   // 8192

// ---- async global->LDS, 16B per lane; LDS dest is wave-uniform base + lane*16 ----
__device__ __forceinline__ void gload16(const void* g, void* l) {
    __builtin_amdgcn_global_load_lds(
        (__attribute__((address_space(1))) void*)(uintptr_t)g,
        (__attribute__((address_space(3))) void*)l,
        16, 0, 0);
}

// T2 swizzle: tile row r (0-255), k-unit cu (0-3, 8 bf16 each) -> byte offset in 32KB tile
__device__ __forceinline__ int swz(int r, int cu) {
    return r * 64 + (((cu ^ (r >> 1)) & 3) << 4);
}

// ---------------- f32 -> bf16 convert (vectorized 4x) ----------------
__global__ void k_cvt(const float* __restrict__ in, bf16* __restrict__ out, int n4) {
    int i = blockIdx.x * blockDim.x + threadIdx.x;
    if (i >= n4) return;
    float4 v = reinterpret_cast<const float4*>(in)[i];
    bf16x4 o = { (bf16)v.x, (bf16)v.y, (bf16)v.z, (bf16)v.w };
    reinterpret_cast<bf16x4*>(out)[i] = o;
}

// ---------------- depthwise conv (k=3, pad 1) over L; writes t_out to d_out ----------------
__global__ void k_conv(const float* __restrict__ x, const float* __restrict__ w,
                       const float* __restrict__ cb, float* __restrict__ out) {
    int idx = blockIdx.x * blockDim.x + threadIdx.x;   // (b*L+l)*512 + dq
    int dq = idx & (D_/4 - 1);
    int bl = idx >> 9;
    int l  = bl & (L_ - 1);
    int d0 = dq * 4;
    const float4* xp = reinterpret_cast<const float4*>(x);
    float4 xc = xp[idx];
    float4 xm = (l > 0)      ? xp[idx - D_/4] : make_float4(0.f,0.f,0.f,0.f);
    float4 xq = (l < L_ - 1) ? xp[idx + D_/4] : make_float4(0.f,0.f,0.f,0.f);
    const float* pm = (const float*)&xm;
    const float* pc = (const float*)&xc;
    const float* pq = (const float*)&xq;
    float4 r;
    float* pr = (float*)&r;
    #pragma unroll
    for (int j = 0; j < 4; ++j) {
        int d = d0 + j;
        pr[j] = pm[j]*w[d*3+0] + pc[j]*w[d*3+1] + pq[j]*w[d*3+2] + cb[d];
    }
    reinterpret_cast<float4*>(out)[idx] = r;
}

// ============ 256x256 GEMM: out[m,n] = sum_k A[m,k]*W[n,k] ============
// BK=32, 4 LDS buffers, prefetch 3 K-tiles ahead, counted vmcnt(8), T2 swizzle,
// T5 setprio, T1 2-D XCD swizzle (grid must be 8 x 32), single merged phase/K-tile.
// EPI: 0 = bias, bf16 | 2 = sigmoid+bias, bf16 | 3 = add into f32 out
template<int EPI>
__global__ __launch_bounds__(512, 2)
void k_gemm2(const bf16* __restrict__ A, const bf16* __restrict__ W,
             const float* __restrict__ bias, bf16* __restrict__ ob,
             float* __restrict__ of, int N, int K)
{
    __shared__ __align__(16) char lds[131072];   // 4 x (A 16KB + B 16KB)
    const int t    = threadIdx.x;
    const int lane = t & 63;
    const int w8   = t >> 6;        // wave 0-7
    const int wr   = w8 >> 2;       // row group (128 rows)
    const int wc   = w8 & 3;        // col group (64 cols)

    // T1: 2-D XCD swizzle. HW dispatches linear id round-robin over 8 XCDs.
    // Give XCD x a 4(bn) x 8(bm) sub-grid -> per-XCD B working set fits L2.
    const int lid  = blockIdx.y * 8 + blockIdx.x;   // grid is (8, 32)
    const int xcd  = lid & 7;
    const int slot = lid >> 3;                       // 0..31
    const int bn   = (xcd & 1) * 4 + (slot & 3);
    const int bm   = (xcd >> 1) * 8 + (slot >> 2);

    const bf16* Ab = A + (size_t)bm * 256 * K;
    const bf16* Wb = W + (size_t)bn * 256 * K;
    const int NT = K >> 5;          // K-tiles of 32 (>= 16 for all our shapes)

    // staging map: thread t stages 16B unit t of each 8KB chunk (128 rows x 64B)
    const int sr0 = t >> 2;                    // row within 128-row half
    const int sc  = t & 3;                     // LDS col-unit (post-swizzle)
    const int scc = (sc ^ (sr0 >> 1)) & 3;     // global col-unit (pre-swizzled source)
    const int fr  = lane & 15;
    const int cu  = lane >> 4;
    const int wbase = w8 << 10;

    const bf16* gaB = Ab + (size_t)sr0 * K + scc * 8;   // + ts*32 per tile
    const bf16* gbB = Wb + (size_t)sr0 * K + scc * 8;

    f32x4 acc[8][4] = {};

    // ---- prologue: stage tiles 0,1,2 into buffers 0,1,2 ----
    #pragma unroll
    for (int p = 0; p < 3; ++p) {
        char* Abuf = lds + p * 32768;
        char* Bbuf = Abuf + 16384;
        const bf16* ga = gaB + p * 32;
        const bf16* gb = gbB + p * 32;
        gload16(ga,                   Abuf + wbase);
        gload16(ga + (size_t)128 * K, Abuf + 8192 + wbase);
        gload16(gb,                   Bbuf + wbase);
        gload16(gb + (size_t)128 * K, Bbuf + 8192 + wbase);
    }
    asm volatile("s_waitcnt vmcnt(8)" ::: "memory");   // tile 0 landed; 1,2 in flight
    __builtin_amdgcn_s_barrier();

    for (int tt = 0; tt < NT; ++tt) {
        const char* Al = lds + (tt & 3) * 32768;
        const char* Bl = Al + 16384;
        char* An = lds + ((tt + 3) & 3) * 32768;   // held tile tt-1: reads done before bar2(tt-1)
        char* Bn = An + 16384;
        int ts = tt + 3; if (ts >= NT) ts = NT - 1;  // clamped tail keeps ledger uniform
        const bf16* ga = gaB + ts * 32;
        const bf16* gb = gbB + ts * 32;

        // ---- merged phase: 12 ds_reads (B first so early MFMAs can start) ----
        bf16x8 bfrag[4], afrag[8];
        #pragma unroll
        for (int n = 0; n < 4; ++n)
            bfrag[n] = *(const bf16x8*)(Bl + swz(wc*64 + n*16 + fr, cu));
        #pragma unroll
        for (int g = 0; g < 8; ++g)
            afrag[g] = *(const bf16x8*)(Al + swz(wr*128 + g*16 + fr, cu));

        // stage tile tt+3
        gload16(ga,                   An + wbase);
        gload16(ga + (size_t)128 * K, An + 8192 + wbase);
        gload16(gb,                   Bn + wbase);
        gload16(gb + (size_t)128 * K, Bn + 8192 + wbase);

        // counted wait: tiles <= tt+1 landed; tt+2, tt+3 (8 loads) stay in flight
        asm volatile("s_waitcnt vmcnt(8)" ::: "memory");
        __builtin_amdgcn_s_barrier();

        __builtin_amdgcn_s_setprio(1);
        #pragma unroll
        for (int g = 0; g < 8; ++g)
            #pragma unroll
            for (int n = 0; n < 4; ++n)
                acc[g][n] = __builtin_amdgcn_mfma_f32_16x16x32_bf16(
                    afrag[g], bfrag[n], acc[g][n], 0, 0, 0);
        __builtin_amdgcn_s_setprio(0);
        __builtin_amdgcn_s_barrier();
    }

    // ---- epilogue ----
    const int fq = lane >> 4;
    #pragma unroll
    for (int g = 0; g < 8; ++g) {
        #pragma unroll
        for (int n = 0; n < 4; ++n) {
            const int row0 = bm*256 + wr*128 + g*16 + fq*4;
            const int col  = bn*256 + wc*64 + n*16 + fr;
            float bb = (EPI == 3) ? 0.f : bias[col];
            #pragma unroll
            for (int j = 0; j < 4; ++j) {
                float v = acc[g][n][j] + bb;
                size_t o = (size_t)(row0 + j) * N + col;
                if      (EPI == 0) ob[o] = (bf16)v;
                else if (EPI == 2) ob[o] = (bf16)(1.f / (1.f + __expf(-v)));
                else               of[o] = of[o] + v;
            }
        }
    }
}

// ---------------- 128x128 2-phase GEMM (kept for N=512 gate GEMM) ----------------
// EPI: 1 = relu+bias, bf16
template<int EPI>
__global__ __launch_bounds__(256)
void k_gemm(const bf16* __restrict__ A, const bf16* __restrict__ W,
            const float* __restrict__ bias, bf16* __restrict__ ob,
            float* __restrict__ of, int N, int K)
{
    __shared__ __align__(16) bf16 As[128 * 32];
    __shared__ __align__(16) bf16 Bs[128 * 32];
    const int t    = threadIdx.x;
    const int lane = t & 63;
    const int wv   = t >> 6;
    const int wr   = wv >> 1, wc = wv & 1;
    const int bm   = blockIdx.y, bn = blockIdx.x;
    const bf16* Ab = A + (size_t)bm * 128 * K;
    const bf16* Wb = W + (size_t)bn * 128 * K;
    const int r0 = t >> 2;
    const int kq = (t & 3) * 8;
    char* ldsA = (char*)As + wv * 1024;
    char* ldsB = (char*)Bs + wv * 1024;

    f32x4 acc[4][4] = {};
    const int fr = lane & 15;
    const int fk = (lane >> 4) * 8;

    for (int kt = 0; kt < K; kt += 32) {
        const bf16* ak = Ab + (size_t)r0 * K + kt + kq;
        const bf16* wk = Wb + (size_t)r0 * K + kt + kq;
        gload16(ak,                 ldsA);
        gload16(ak + (size_t)64*K,  ldsA + 4096);
        gload16(wk,                 ldsB);
        gload16(wk + (size_t)64*K,  ldsB + 4096);
        __syncthreads();
        bf16x8 af[4], bw[4];
        #pragma unroll
        for (int i = 0; i < 4; ++i) {
            af[i] = *(const bf16x8*)&As[(wr*64 + i*16 + fr) * 32 + fk];
            bw[i] = *(const bf16x8*)&Bs[(wc*64 + i*16 + fr) * 32 + fk];
        }
        #pragma unroll
        for (int mi = 0; mi < 4; ++mi)
            #pragma unroll
            for (int ni = 0; ni < 4; ++ni)
                acc[mi][ni] = __builtin_amdgcn_mfma_f32_16x16x32_bf16(
                    af[mi], bw[ni], acc[mi][ni], 0, 0, 0);
        __syncthreads();
    }

    const int fq = lane >> 4;
    #pragma unroll
    for (int mi = 0; mi < 4; ++mi) {
        #pragma unroll
        for (int ni = 0; ni < 4; ++ni) {
            const int row0 = bm*128 + wr*64 + mi*16 + fq*4;
            const int col  = bn*128 + wc*64 + ni*16 + fr;
            float bb = bias[col];
            #pragma unroll
            for (int j = 0; j < 4; ++j) {
                float v = acc[mi][ni][j] + bb;
                size_t o = (size_t)(row0 + j) * N + col;
                ob[o] = (bf16)fmaxf(v, 0.f);
            }
        }
    }
}

// ---------------- prefix scan over L, split into 16 chunks of 128 ----------------
__global__ void k_scan_sum(const bf16* __restrict__ U, const bf16* __restrict__ G,
                           float* __restrict__ CS) {
    int idx = blockIdx.x * blockDim.x + threadIdx.x;   // B*16*R = 131072
    int r  = idx & (R_ - 1);
    int ch = (idx >> 11) & 15;
    int b  = idx >> 15;
    size_t base = ((size_t)(b * L_ + ch * 128)) * R_ + r;
    float s = 0.f;
    #pragma unroll 8
    for (int i = 0; i < 128; ++i) {
        float u = (float)U[base + (size_t)i * R_];
        float g = (float)G[base + (size_t)i * R_];
        s = fmaf(u, g, s);
    }
    CS[idx] = s;
}

__global__ void k_scan_apply(const bf16* __restrict__ U, const bf16* __restrict__ V,
                             const bf16* __restrict__ G, const float* __restrict__ CS,
                             bf16* __restrict__ GB) {
    int idx = blockIdx.x * blockDim.x + threadIdx.x;
    int r  = idx & (R_ - 1);
    int ch = (idx >> 11) & 15;
    int b  = idx >> 15;
    float run = 0.f;
    for (int c = 0; c < ch; ++c)
        run += CS[(((b << 4) + c) << 11) + r];
    size_t base = ((size_t)(b * L_ + ch * 128)) * R_ + r;
    #pragma unroll 4
    for (int i = 0; i < 128; ++i) {
        size_t o = base + (size_t)i * R_;
        float u = (float)U[o];
        float g = (float)G[o];
        float v = (float)V[o];
        run = fmaf(u, g, run);
        GB[o] = (bf16)(run * v * g);
    }
}

extern "C" void kernel_launch(void* const* d_in, const int* in_sizes, int n_in,
                              void* d_out, int out_size, void* d_ws, size_t ws_size,
                              hipStream_t stream)
{
    const float* x   = (const float*)d_in[0];
    const float* Wu  = (const float*)d_in[1];
    const float* bu  = (const float*)d_in[2];
    const float* Wv  = (const float*)d_in[3];
    const float* bv  = (const float*)d_in[4];
    const float* Wg1 = (const float*)d_in[5];
    const float* bg1 = (const float*)d_in[6];
    const float* Wg2 = (const float*)d_in[7];
    const float* bg2 = (const float*)d_in[8];
    const float* cw  = (const float*)d_in[9];
    const float* cb  = (const float*)d_in[10];
    float* out = (float*)d_out;

    char* w = (char*)d_ws;
    bf16* xb   = (bf16*)w;  w += (size_t)M_ * D_  * 2;
    bf16* Wub  = (bf16*)w;  w += (size_t)R_ * D_  * 2;
    bf16* Wvb  = (bf16*)w;  w += (size_t)R_ * D_  * 2;
    bf16* Wg1b = (bf16*)w;  w += (size_t)DH_* D_  * 2;
    bf16* Wg2b = (bf16*)w;  w += (size_t)R_ * DH_ * 2;
    bf16* U    = (bf16*)w;  w += (size_t)M_ * R_  * 2;
    bf16* V    = (bf16*)w;  w += (size_t)M_ * R_  * 2;
    bf16* H    = (bf16*)w;  w += (size_t)M_ * DH_ * 2;
    bf16* GT   = (bf16*)w;  w += (size_t)M_ * R_  * 2;
    bf16* GB   = (bf16*)w;  w += (size_t)M_ * R_  * 2;
    float* CS  = (float*)w; w += (size_t)B_ * 16 * R_ * 4;

    // converts
    k_cvt<<<M_*D_/4/256,  256, 0, stream>>>(x,   xb,   M_*D_/4);
    k_cvt<<<R_*D_/4/256,  256, 0, stream>>>(Wu,  Wub,  R_*D_/4);
    k_cvt<<<R_*D_/4/256,  256, 0, stream>>>(Wv,  Wvb,  R_*D_/4);
    k_cvt<<<DH_*D_/4/256, 256, 0, stream>>>(Wg1, Wg1b, DH_*D_/4);
    k_cvt<<<R_*DH_/4/256, 256, 0, stream>>>(Wg2, Wg2b, R_*DH_/4);

    // depthwise conv -> d_out (t_out term)
    k_conv<<<M_*D_/4/256, 256, 0, stream>>>(x, cw, cb, out);

    // projections (256^2 pipelined kernel for the N=2048 GEMMs)
    k_gemm2<0><<<dim3(R_/256,  M_/256), 512, 0, stream>>>(xb, Wub,  bu,  U,  nullptr, R_,  D_);
    k_gemm2<0><<<dim3(R_/256,  M_/256), 512, 0, stream>>>(xb, Wvb,  bv,  V,  nullptr, R_,  D_);
    k_gemm<1> <<<dim3(DH_/128, M_/128), 256, 0, stream>>>(xb, Wg1b, bg1, H,  nullptr, DH_, D_);
    k_gemm2<2><<<dim3(R_/256,  M_/256), 512, 0, stream>>>(H,  Wg2b, bg2, GT, nullptr, R_,  DH_);

    // gated prefix scan -> GB = cumsum(u*g) * (v*g)
    k_scan_sum  <<<B_*16*R_/256, 256, 0, stream>>>(U, GT, CS);
    k_scan_apply<<<B_*16*R_/256, 256, 0, stream>>>(U, V, GT, CS, GB);

    // uv_term: d_out += GB @ Wu^T
    k_gemm2<3><<<dim3(D_/256, M_/256), 512, 0, stream>>>(GB, Wub, nullptr, nullptr, out, D_, R_);
}